// Round 7
// baseline (635.654 us; speedup 1.0000x reference)
//
#include <hip/hip_runtime.h>

#define N_NODES 50000
#define N_EDGES 800000
#define D 128
#define HEADS 8

typedef __attribute__((ext_vector_type(8))) short short8b;  // 8 bf16 (4 VGPRs)
typedef __attribute__((ext_vector_type(4))) float f32x4;

__device__ __forceinline__ unsigned short f2bf_rne(float f) {
    unsigned int u = __float_as_uint(f);
    u += 0x7FFFu + ((u >> 16) & 1u);   // round-to-nearest-even
    return (unsigned short)(u >> 16);
}
__device__ __forceinline__ float bf2f(unsigned short u) {
    return __uint_as_float(((unsigned int)u) << 16);
}

// ---------------- K1 (MFMA): hs/hr = bf16(nodes @ W + b) --------------------
#define K1_ROWS 256
__global__ __launch_bounds__(256, 3) void k_node_proj_mfma(
    const float* __restrict__ nodes,
    const float* __restrict__ Ws, const float* __restrict__ bs,
    const float* __restrict__ Wr, const float* __restrict__ br,
    unsigned short* __restrict__ hsb, unsigned short* __restrict__ hrb)
{
    __shared__ __align__(16) unsigned short WT[D][136];   // [col][k] 34816 B
    __shared__ __align__(16) unsigned short At[64][136];  // [row][k] 17408 B
    const int ntiles = (N_NODES + K1_ROWS - 1) / K1_ROWS;   // 196
    int bx = blockIdx.x;
    int proj = (bx >= ntiles) ? 1 : 0;
    int tile = proj ? (bx - ntiles) : bx;
    const float* W    = proj ? Wr : Ws;
    const float* bias = proj ? br : bs;
    unsigned short* outp = proj ? hrb : hsb;
    int t = threadIdx.x;
    int lane = t & 63;
    int wv = t >> 6;
    int lg = lane >> 4;
    int li = lane & 15;

    #pragma unroll 8
    for (int j = 0; j < 64; ++j) {
        int idx = t + 256 * j;     // k*128+c
        int k = idx >> 7, c = idx & 127;
        WT[c][k] = f2bf_rne(W[idx]);
    }
    float b_ct[8];
    #pragma unroll
    for (int ct = 0; ct < 8; ++ct) b_ct[ct] = bias[ct * 16 + li];

    #pragma unroll 1
    for (int sub = 0; sub < 4; ++sub) {
        int row0 = tile * K1_ROWS + sub * 64;
        if (row0 >= N_NODES) break;          // uniform
        __syncthreads();
        {   // stage 64 node rows -> bf16 LDS
            const float4* Nv = (const float4*)nodes;
            #pragma unroll
            for (int j = 0; j < 8; ++j) {
                int fi = t + 256 * j;
                int r = row0 + (fi >> 5);
                float4 v = make_float4(0.f, 0.f, 0.f, 0.f);
                if (r < N_NODES) v = Nv[(size_t)r * 32 + (fi & 31)];
                ushort4 b;
                b.x = f2bf_rne(v.x); b.y = f2bf_rne(v.y);
                b.z = f2bf_rne(v.z); b.w = f2bf_rne(v.w);
                *(ushort4*)&At[fi >> 5][(fi & 31) * 4] = b;
            }
        }
        __syncthreads();

        short8b afr[4];
        #pragma unroll
        for (int kb = 0; kb < 4; ++kb)
            afr[kb] = *(const short8b*)&At[wv * 16 + li][kb * 32 + lg * 8];

        #pragma unroll
        for (int ct = 0; ct < 8; ++ct) {
            f32x4 acc = {0.f, 0.f, 0.f, 0.f};
            #pragma unroll
            for (int kb = 0; kb < 4; ++kb) {
                short8b bfr = *(const short8b*)&WT[ct * 16 + li][kb * 32 + lg * 8];
                acc = __builtin_amdgcn_mfma_f32_16x16x32_bf16(afr[kb], bfr, acc, 0, 0, 0);
            }
            #pragma unroll
            for (int j = 0; j < 4; ++j) {
                int r = row0 + wv * 16 + lg * 4 + j;
                if (r < N_NODES)
                    outp[(size_t)r * D + ct * 16 + li] = f2bf_rne(acc[j] + b_ct[ct]);
            }
        }
    }
}

// ------------------------- CSR build (runs before K2) ------------------------
__global__ __launch_bounds__(256) void k_hist(
    const int* __restrict__ receivers, int* __restrict__ deg)
{
    int i = blockIdx.x * 256 + threadIdx.x;
    if (i < N_EDGES) atomicAdd(&deg[receivers[i]], 1);
}

#define SCAN_CHUNK 49
__global__ __launch_bounds__(1024) void k_scan(
    const int* __restrict__ deg, int* __restrict__ rowptr, int* __restrict__ cursor)
{
    __shared__ int sm[1024];
    int t = threadIdx.x;
    int base = t * SCAN_CHUNK;
    int lsum = 0;
    #pragma unroll 4
    for (int i = 0; i < SCAN_CHUNK; ++i) {
        int idx = base + i;
        if (idx < N_NODES) lsum += deg[idx];
    }
    sm[t] = lsum;
    __syncthreads();
    for (int off = 1; off < 1024; off <<= 1) {
        int v = (t >= off) ? sm[t - off] : 0;
        __syncthreads();
        sm[t] += v;
        __syncthreads();
    }
    int run = (t > 0) ? sm[t - 1] : 0;
    for (int i = 0; i < SCAN_CHUNK; ++i) {
        int idx = base + i;
        if (idx < N_NODES) {
            rowptr[idx] = run;
            cursor[idx] = run;
            run += deg[idx];
        }
    }
    if (t == 1023) rowptr[N_NODES] = sm[1023];
}

__global__ __launch_bounds__(256) void k_fill(
    const int* __restrict__ receivers, const int* __restrict__ senders,
    int* __restrict__ cursor,
    int* __restrict__ eids, int* __restrict__ s_csr, int* __restrict__ r_csr)
{
    int i = blockIdx.x * 256 + threadIdx.x;
    if (i < N_EDGES) {
        int r = receivers[i];
        int pos = atomicAdd(&cursor[r], 1);
        eids[pos]  = i;
        s_csr[pos] = senders[i];
        r_csr[pos] = r;
    }
}

// ------- K2 (MFMA bf16, CSR order, barrier-free): logits -> ex ---------------
// A-fragments built directly from global (no Et LDS, no per-tile barriers).
// Lane (lg,li) of wave wv: A row = edge (wv*16+li), k-slice = kb*32+lg*8.
#define BLK_E 64
__global__ __launch_bounds__(256, 3) void k_edge_logits_mfma(
    const float* __restrict__ edges,
    const int* __restrict__ eids, const int* __restrict__ s_csr,
    const int* __restrict__ r_csr,
    const float* __restrict__ We, const float* __restrict__ be,
    const float* __restrict__ a,
    const unsigned short* __restrict__ hsb, const unsigned short* __restrict__ hrb,
    float* __restrict__ ex)
{
    __shared__ __align__(16) unsigned short WeT[D][136];    // [col][k] 34816 B
    int t = threadIdx.x;
    int lane = t & 63;
    int wv = t >> 6;
    int lg = lane >> 4;
    int li = lane & 15;

    #pragma unroll 8
    for (int j = 0; j < 64; ++j) {
        int idx = t + 256 * j;
        int k = idx >> 7, c = idx & 127;
        WeT[c][k] = f2bf_rne(We[idx]);
    }
    float a_h[HEADS], be_h[HEADS];
    #pragma unroll
    for (int h = 0; h < HEADS; ++h) {
        a_h[h]  = a[h * 16 + li];
        be_h[h] = be[h * 16 + li];
    }
    int jm = li & 3;
    __syncthreads();   // WeT ready; the ONLY barrier in this kernel

    const int ntiles = N_EDGES / BLK_E;   // 12500
    for (int tile = blockIdx.x; tile < ntiles; tile += gridDim.x) {
        int pbase = tile * BLK_E + wv * 16;

        // independent index loads first (broadcast/coalesced)
        int erow = eids[pbase + li];         // A-fragment row for this lane
        int sj[4], rj[4];
        #pragma unroll
        for (int j = 0; j < 4; ++j) {
            sj[j] = s_csr[pbase + lg * 4 + j];
            rj[j] = r_csr[pbase + lg * 4 + j];
        }

        // edge row k-slices straight from global (8x float4, independent)
        float4 ea[4][2];
        {
            const float* erp = edges + (size_t)erow * D + lg * 8;
            #pragma unroll
            for (int kb = 0; kb < 4; ++kb) {
                ea[kb][0] = *(const float4*)(erp + kb * 32);
                ea[kb][1] = *(const float4*)(erp + kb * 32 + 4);
            }
        }
        // hs/hr gathers (hr mostly L1-local in CSR order)
        unsigned short g_hs[4][HEADS], g_hr[4][HEADS];
        #pragma unroll
        for (int j = 0; j < 4; ++j) {
            const unsigned short* hsrow = hsb + (size_t)sj[j] * D + li;
            const unsigned short* hrrow = hrb + (size_t)rj[j] * D + li;
            #pragma unroll
            for (int h = 0; h < HEADS; ++h) {
                g_hs[j][h] = hsrow[h * 16];
                g_hr[j][h] = hrrow[h * 16];
            }
        }

        // pack A-fragments bf16
        short8b afr[4];
        #pragma unroll
        for (int kb = 0; kb < 4; ++kb) {
            afr[kb][0] = (short)f2bf_rne(ea[kb][0].x);
            afr[kb][1] = (short)f2bf_rne(ea[kb][0].y);
            afr[kb][2] = (short)f2bf_rne(ea[kb][0].z);
            afr[kb][3] = (short)f2bf_rne(ea[kb][0].w);
            afr[kb][4] = (short)f2bf_rne(ea[kb][1].x);
            afr[kb][5] = (short)f2bf_rne(ea[kb][1].y);
            afr[kb][6] = (short)f2bf_rne(ea[kb][1].z);
            afr[kb][7] = (short)f2bf_rne(ea[kb][1].w);
        }

        #pragma unroll
        for (int h = 0; h < HEADS; ++h) {
            f32x4 acc = {0.f, 0.f, 0.f, 0.f};
            #pragma unroll
            for (int kb = 0; kb < 4; ++kb) {
                short8b bfr = *(const short8b*)&WeT[h * 16 + li][kb * 32 + lg * 8];
                acc = __builtin_amdgcn_mfma_f32_16x16x32_bf16(afr[kb], bfr, acc, 0, 0, 0);
            }
            float p[4];
            #pragma unroll
            for (int j = 0; j < 4; ++j) {
                float x = acc[j] + be_h[h] + bf2f(g_hs[j][h]) + bf2f(g_hr[j][h]);
                x = x > 0.f ? x : 0.01f * x;
                p[j] = x * a_h[h];
            }
            #pragma unroll
            for (int j = 0; j < 4; ++j) {
                p[j] += __shfl_xor(p[j], 1);
                p[j] += __shfl_xor(p[j], 2);
            }
            float q = (jm & 1) ? ((jm & 2) ? p[3] : p[1])
                               : ((jm & 2) ? p[2] : p[0]);
            q += __shfl_xor(q, 4);
            q += __shfl_xor(q, 8);
            float e_ = __expf(q);
            if (li < 4) {
                int pos = pbase + lg * 4 + li;
                ex[(size_t)pos * HEADS + h] = e_;    // CSR-contiguous write
            }
        }
    }
}

// ---------- K3: per-node gather; s_csr/ex contiguous, hs random -------------
__global__ __launch_bounds__(256) void k_gather_out(
    const int* __restrict__ rowptr, const int* __restrict__ s_csr,
    const unsigned short* __restrict__ hsb, const float* __restrict__ ex,
    float* __restrict__ out)
{
    int r = blockIdx.x * 4 + (threadIdx.x >> 6);
    int l = threadIdx.x & 63;
    int h = l >> 3;
    int beg = rowptr[r], end = rowptr[r + 1];

    float2 acc = make_float2(0.f, 0.f);
    float dsum = 0.f;
    for (int j0 = beg; j0 < end; j0 += 16) {
        int cnt = end - j0;
        int s[16]; float w[16];
        #pragma unroll
        for (int q = 0; q < 16; ++q)
            if (q < cnt) { s[q] = s_csr[j0 + q]; w[q] = ex[(size_t)(j0 + q) * HEADS + h]; }
        #pragma unroll
        for (int q = 0; q < 16; ++q)
            if (q < cnt) {
                ushort2 hv = *(const ushort2*)&hsb[(size_t)s[q] * D + 2 * l];
                acc.x += w[q] * bf2f(hv.x);
                acc.y += w[q] * bf2f(hv.y);
                dsum  += w[q];
            }
    }
    float inv = (end > beg && dsum != 0.f) ? (1.0f / dsum) : 0.f;
    acc.x *= inv; acc.y *= inv;
    *(float2*)&out[(size_t)r * D + 2 * l] = acc;
}

extern "C" void kernel_launch(void* const* d_in, const int* in_sizes, int n_in,
                              void* d_out, int out_size, void* d_ws, size_t ws_size,
                              hipStream_t stream) {
    const float* nodes     = (const float*)d_in[0];
    const float* edges     = (const float*)d_in[1];
    const int*   senders   = (const int*)d_in[2];
    const int*   receivers = (const int*)d_in[3];
    const float* Ws = (const float*)d_in[4];
    const float* bs = (const float*)d_in[5];
    const float* Wr = (const float*)d_in[6];
    const float* br = (const float*)d_in[7];
    const float* We = (const float*)d_in[8];
    const float* be = (const float*)d_in[9];
    const float* a  = (const float*)d_in[10];
    float* out = (float*)d_out;

    unsigned short* hsb = (unsigned short*)d_ws;          // 6.4M bf16
    unsigned short* hrb = hsb + (size_t)N_NODES * D;      // 6.4M bf16
    float* ex   = (float*)(hrb + (size_t)N_NODES * D);    // 6.4M f32 (CSR order)
    int* deg    = (int*)(ex + (size_t)N_EDGES * HEADS);   // 50000
    int* rowptr = deg + N_NODES;                          // 50001
    int* cursor = rowptr + N_NODES + 1;                   // 50000
    int* eids   = cursor + N_NODES;                       // 800000
    int* s_csr  = eids + N_EDGES;                         // 800000
    int* r_csr  = s_csr + N_EDGES;                        // 800000

    hipMemsetAsync(deg, 0, N_NODES * sizeof(int), stream);
    k_hist<<<N_EDGES / 256, 256, 0, stream>>>(receivers, deg);
    k_scan<<<1, 1024, 0, stream>>>(deg, rowptr, cursor);
    k_fill<<<N_EDGES / 256, 256, 0, stream>>>(receivers, senders, cursor,
                                              eids, s_csr, r_csr);
    int ntiles_n = (N_NODES + K1_ROWS - 1) / K1_ROWS;
    k_node_proj_mfma<<<ntiles_n * 2, 256, 0, stream>>>(nodes, Ws, bs, Wr, br, hsb, hrb);
    k_edge_logits_mfma<<<768, 256, 0, stream>>>(edges, eids, s_csr, r_csr,
                                                We, be, a, hsb, hrb, ex);
    k_gather_out<<<N_NODES / 4, 256, 0, stream>>>(rowptr, s_csr, hsb, ex, out);
}

// Round 8
// 462.537 us; speedup vs baseline: 1.3743x; 1.3743x over previous
//
#include <hip/hip_runtime.h>

#define N_NODES 50000
#define N_EDGES 800000
#define D 128
#define HEADS 8

typedef __attribute__((ext_vector_type(8))) short short8b;  // 8 bf16 (4 VGPRs)
typedef __attribute__((ext_vector_type(4))) float f32x4;

__device__ __forceinline__ unsigned short f2bf_rne(float f) {
    unsigned int u = __float_as_uint(f);
    u += 0x7FFFu + ((u >> 16) & 1u);   // round-to-nearest-even
    return (unsigned short)(u >> 16);
}
__device__ __forceinline__ float bf2f(unsigned short u) {
    return __uint_as_float(((unsigned int)u) << 16);
}

// ---------------- K1 (MFMA): hs/hr = bf16(nodes @ W + b) --------------------
#define K1_ROWS 256
__global__ __launch_bounds__(256, 3) void k_node_proj_mfma(
    const float* __restrict__ nodes,
    const float* __restrict__ Ws, const float* __restrict__ bs,
    const float* __restrict__ Wr, const float* __restrict__ br,
    unsigned short* __restrict__ hsb, unsigned short* __restrict__ hrb)
{
    __shared__ __align__(16) unsigned short WT[D][136];   // [col][k] 34816 B
    __shared__ __align__(16) unsigned short At[64][136];  // [row][k] 17408 B
    const int ntiles = (N_NODES + K1_ROWS - 1) / K1_ROWS;   // 196
    int bx = blockIdx.x;
    int proj = (bx >= ntiles) ? 1 : 0;
    int tile = proj ? (bx - ntiles) : bx;
    const float* W    = proj ? Wr : Ws;
    const float* bias = proj ? br : bs;
    unsigned short* outp = proj ? hrb : hsb;
    int t = threadIdx.x;
    int lane = t & 63;
    int wv = t >> 6;
    int lg = lane >> 4;
    int li = lane & 15;

    #pragma unroll 8
    for (int j = 0; j < 64; ++j) {
        int idx = t + 256 * j;     // k*128+c
        int k = idx >> 7, c = idx & 127;
        WT[c][k] = f2bf_rne(W[idx]);
    }
    float b_ct[8];
    #pragma unroll
    for (int ct = 0; ct < 8; ++ct) b_ct[ct] = bias[ct * 16 + li];

    #pragma unroll 1
    for (int sub = 0; sub < 4; ++sub) {
        int row0 = tile * K1_ROWS + sub * 64;
        if (row0 >= N_NODES) break;          // uniform
        __syncthreads();
        {   // stage 64 node rows -> bf16 LDS
            const float4* Nv = (const float4*)nodes;
            #pragma unroll
            for (int j = 0; j < 8; ++j) {
                int fi = t + 256 * j;
                int r = row0 + (fi >> 5);
                float4 v = make_float4(0.f, 0.f, 0.f, 0.f);
                if (r < N_NODES) v = Nv[(size_t)r * 32 + (fi & 31)];
                ushort4 b;
                b.x = f2bf_rne(v.x); b.y = f2bf_rne(v.y);
                b.z = f2bf_rne(v.z); b.w = f2bf_rne(v.w);
                *(ushort4*)&At[fi >> 5][(fi & 31) * 4] = b;
            }
        }
        __syncthreads();

        short8b afr[4];
        #pragma unroll
        for (int kb = 0; kb < 4; ++kb)
            afr[kb] = *(const short8b*)&At[wv * 16 + li][kb * 32 + lg * 8];

        #pragma unroll
        for (int ct = 0; ct < 8; ++ct) {
            f32x4 acc = {0.f, 0.f, 0.f, 0.f};
            #pragma unroll
            for (int kb = 0; kb < 4; ++kb) {
                short8b bfr = *(const short8b*)&WT[ct * 16 + li][kb * 32 + lg * 8];
                acc = __builtin_amdgcn_mfma_f32_16x16x32_bf16(afr[kb], bfr, acc, 0, 0, 0);
            }
            #pragma unroll
            for (int j = 0; j < 4; ++j) {
                int r = row0 + wv * 16 + lg * 4 + j;
                if (r < N_NODES)
                    outp[(size_t)r * D + ct * 16 + li] = f2bf_rne(acc[j] + b_ct[ct]);
            }
        }
    }
}

// ------------------------- CSR build (runs before K2) ------------------------
__global__ __launch_bounds__(256) void k_hist(
    const int* __restrict__ receivers, int* __restrict__ deg)
{
    int i = blockIdx.x * 256 + threadIdx.x;
    if (i < N_EDGES) atomicAdd(&deg[receivers[i]], 1);
}

#define SCAN_CHUNK 49
__global__ __launch_bounds__(1024) void k_scan(
    const int* __restrict__ deg, int* __restrict__ rowptr, int* __restrict__ cursor)
{
    __shared__ int sm[1024];
    int t = threadIdx.x;
    int base = t * SCAN_CHUNK;
    int lsum = 0;
    #pragma unroll 4
    for (int i = 0; i < SCAN_CHUNK; ++i) {
        int idx = base + i;
        if (idx < N_NODES) lsum += deg[idx];
    }
    sm[t] = lsum;
    __syncthreads();
    for (int off = 1; off < 1024; off <<= 1) {
        int v = (t >= off) ? sm[t - off] : 0;
        __syncthreads();
        sm[t] += v;
        __syncthreads();
    }
    int run = (t > 0) ? sm[t - 1] : 0;
    for (int i = 0; i < SCAN_CHUNK; ++i) {
        int idx = base + i;
        if (idx < N_NODES) {
            rowptr[idx] = run;
            cursor[idx] = run;
            run += deg[idx];
        }
    }
    if (t == 1023) rowptr[N_NODES] = sm[1023];
}

__global__ __launch_bounds__(256) void k_fill(
    const int* __restrict__ receivers, const int* __restrict__ senders,
    int* __restrict__ cursor,
    int* __restrict__ eids, int* __restrict__ s_csr, int* __restrict__ r_csr)
{
    int i = blockIdx.x * 256 + threadIdx.x;
    if (i < N_EDGES) {
        int r = receivers[i];
        int pos = atomicAdd(&cursor[r], 1);
        eids[pos]  = i;
        s_csr[pos] = senders[i];
        r_csr[pos] = r;
    }
}

// ------- K2 (MFMA bf16, CSR order, wave-local staging, barrier-free) ---------
// Wave wv stages ITS OWN 16 edge rows (coalesced 512B row reads) into its own
// Et quarter and reads only that quarter -> no cross-wave LDS sharing, no
// per-tile __syncthreads. Intra-wave write->read ordered by lgkmcnt(0).
#define BLK_E 64
__global__ __launch_bounds__(256, 3) void k_edge_logits_mfma(
    const float* __restrict__ edges,
    const int* __restrict__ eids, const int* __restrict__ s_csr,
    const int* __restrict__ r_csr,
    const float* __restrict__ We, const float* __restrict__ be,
    const float* __restrict__ a,
    const unsigned short* __restrict__ hsb, const unsigned short* __restrict__ hrb,
    float* __restrict__ ex)
{
    __shared__ __align__(16) unsigned short WeT[D][136];    // [col][k] 34816 B
    __shared__ __align__(16) unsigned short Et[BLK_E][136]; // [edge][k] 17408 B
    int t = threadIdx.x;
    int lane = t & 63;
    int wv = t >> 6;
    int lg = lane >> 4;
    int li = lane & 15;

    #pragma unroll 8
    for (int j = 0; j < 64; ++j) {
        int idx = t + 256 * j;
        int k = idx >> 7, c = idx & 127;
        WeT[c][k] = f2bf_rne(We[idx]);
    }
    float a_h[HEADS], be_h[HEADS];
    #pragma unroll
    for (int h = 0; h < HEADS; ++h) {
        a_h[h]  = a[h * 16 + li];
        be_h[h] = be[h * 16 + li];
    }
    int jm = li & 3;
    __syncthreads();   // WeT ready; the ONLY block barrier

    const int ntiles = N_EDGES / BLK_E;   // 12500
    for (int tile = blockIdx.x; tile < ntiles; tile += gridDim.x) {
        int pbase = tile * BLK_E + wv * 16;   // this wave's 16 CSR rows

        // stage this wave's 16 edge rows -> bf16 LDS (each 512B row read by
        // 32 consecutive lanes: fully coalesced)
        {
            const float4* Ev = (const float4*)edges;
            #pragma unroll
            for (int j = 0; j < 8; ++j) {
                int fi = lane + 64 * j;        // 0..511
                int rloc = fi >> 5;            // 0..15
                int e = eids[pbase + rloc];    // L1 broadcast
                float4 v = Ev[(size_t)e * 32 + (fi & 31)];
                ushort4 b;
                b.x = f2bf_rne(v.x); b.y = f2bf_rne(v.y);
                b.z = f2bf_rne(v.z); b.w = f2bf_rne(v.w);
                *(ushort4*)&Et[wv * 16 + rloc][(fi & 31) * 4] = b;
            }
        }

        // independent vmem while LDS writes drain
        int sj[4], rj[4];
        #pragma unroll
        for (int j = 0; j < 4; ++j) {
            sj[j] = s_csr[pbase + lg * 4 + j];
            rj[j] = r_csr[pbase + lg * 4 + j];
        }
        unsigned short g_hs[4][HEADS], g_hr[4][HEADS];
        #pragma unroll
        for (int j = 0; j < 4; ++j) {
            const unsigned short* hsrow = hsb + (size_t)sj[j] * D + li;
            const unsigned short* hrrow = hrb + (size_t)rj[j] * D + li;
            #pragma unroll
            for (int h = 0; h < HEADS; ++h) {
                g_hs[j][h] = hsrow[h * 16];
                g_hr[j][h] = hrrow[h * 16];
            }
        }

        // intra-wave LDS write->read fence (no block barrier needed)
        asm volatile("s_waitcnt lgkmcnt(0)" ::: "memory");
        __builtin_amdgcn_sched_barrier(0);

        short8b afr[4];
        #pragma unroll
        for (int kb = 0; kb < 4; ++kb)
            afr[kb] = *(const short8b*)&Et[wv * 16 + li][kb * 32 + lg * 8];

        #pragma unroll
        for (int h = 0; h < HEADS; ++h) {
            f32x4 acc = {0.f, 0.f, 0.f, 0.f};
            #pragma unroll
            for (int kb = 0; kb < 4; ++kb) {
                short8b bfr = *(const short8b*)&WeT[h * 16 + li][kb * 32 + lg * 8];
                acc = __builtin_amdgcn_mfma_f32_16x16x32_bf16(afr[kb], bfr, acc, 0, 0, 0);
            }
            float p[4];
            #pragma unroll
            for (int j = 0; j < 4; ++j) {
                float x = acc[j] + be_h[h] + bf2f(g_hs[j][h]) + bf2f(g_hr[j][h]);
                x = x > 0.f ? x : 0.01f * x;
                p[j] = x * a_h[h];
            }
            #pragma unroll
            for (int j = 0; j < 4; ++j) {
                p[j] += __shfl_xor(p[j], 1);
                p[j] += __shfl_xor(p[j], 2);
            }
            float q = (jm & 1) ? ((jm & 2) ? p[3] : p[1])
                               : ((jm & 2) ? p[2] : p[0]);
            q += __shfl_xor(q, 4);
            q += __shfl_xor(q, 8);
            float e_ = __expf(q);
            if (li < 4) {
                int pos = pbase + lg * 4 + li;
                ex[(size_t)pos * HEADS + h] = e_;    // CSR-contiguous write
            }
        }
        // keep this tile's afr reads ordered before next tile's Et writes
        __builtin_amdgcn_wave_barrier();
    }
}

// ---------- K3: per-node gather; s_csr/ex contiguous, hs random -------------
__global__ __launch_bounds__(256) void k_gather_out(
    const int* __restrict__ rowptr, const int* __restrict__ s_csr,
    const unsigned short* __restrict__ hsb, const float* __restrict__ ex,
    float* __restrict__ out)
{
    int r = blockIdx.x * 4 + (threadIdx.x >> 6);
    int l = threadIdx.x & 63;
    int h = l >> 3;
    int beg = rowptr[r], end = rowptr[r + 1];

    float2 acc = make_float2(0.f, 0.f);
    float dsum = 0.f;
    for (int j0 = beg; j0 < end; j0 += 16) {
        int cnt = end - j0;
        int s[16]; float w[16];
        #pragma unroll
        for (int q = 0; q < 16; ++q)
            if (q < cnt) { s[q] = s_csr[j0 + q]; w[q] = ex[(size_t)(j0 + q) * HEADS + h]; }
        #pragma unroll
        for (int q = 0; q < 16; ++q)
            if (q < cnt) {
                ushort2 hv = *(const ushort2*)&hsb[(size_t)s[q] * D + 2 * l];
                acc.x += w[q] * bf2f(hv.x);
                acc.y += w[q] * bf2f(hv.y);
                dsum  += w[q];
            }
    }
    float inv = (end > beg && dsum != 0.f) ? (1.0f / dsum) : 0.f;
    acc.x *= inv; acc.y *= inv;
    *(float2*)&out[(size_t)r * D + 2 * l] = acc;
}

extern "C" void kernel_launch(void* const* d_in, const int* in_sizes, int n_in,
                              void* d_out, int out_size, void* d_ws, size_t ws_size,
                              hipStream_t stream) {
    const float* nodes     = (const float*)d_in[0];
    const float* edges     = (const float*)d_in[1];
    const int*   senders   = (const int*)d_in[2];
    const int*   receivers = (const int*)d_in[3];
    const float* Ws = (const float*)d_in[4];
    const float* bs = (const float*)d_in[5];
    const float* Wr = (const float*)d_in[6];
    const float* br = (const float*)d_in[7];
    const float* We = (const float*)d_in[8];
    const float* be = (const float*)d_in[9];
    const float* a  = (const float*)d_in[10];
    float* out = (float*)d_out;

    unsigned short* hsb = (unsigned short*)d_ws;          // 6.4M bf16
    unsigned short* hrb = hsb + (size_t)N_NODES * D;      // 6.4M bf16
    float* ex   = (float*)(hrb + (size_t)N_NODES * D);    // 6.4M f32 (CSR order)
    int* deg    = (int*)(ex + (size_t)N_EDGES * HEADS);   // 50000
    int* rowptr = deg + N_NODES;                          // 50001
    int* cursor = rowptr + N_NODES + 1;                   // 50000
    int* eids   = cursor + N_NODES;                       // 800000
    int* s_csr  = eids + N_EDGES;                         // 800000
    int* r_csr  = s_csr + N_EDGES;                        // 800000

    hipMemsetAsync(deg, 0, N_NODES * sizeof(int), stream);
    k_hist<<<N_EDGES / 256, 256, 0, stream>>>(receivers, deg);
    k_scan<<<1, 1024, 0, stream>>>(deg, rowptr, cursor);
    k_fill<<<N_EDGES / 256, 256, 0, stream>>>(receivers, senders, cursor,
                                              eids, s_csr, r_csr);
    int ntiles_n = (N_NODES + K1_ROWS - 1) / K1_ROWS;
    k_node_proj_mfma<<<ntiles_n * 2, 256, 0, stream>>>(nodes, Ws, bs, Wr, br, hsb, hrb);
    k_edge_logits_mfma<<<2048, 256, 0, stream>>>(edges, eids, s_csr, r_csr,
                                                 We, be, a, hsb, hrb, ex);
    k_gather_out<<<N_NODES / 4, 256, 0, stream>>>(rowptr, s_csr, hsb, ex, out);
}